// Round 1
// baseline (1829.140 us; speedup 1.0000x reference)
//
#include <hip/hip_runtime.h>

// Portfolio PGD: B=4096 batches, n=104 assets, fp32.
// 1 wave (64 threads) per batch. Thread l owns Sigma rows l and 64+l in VGPRs
// (208 regs). __launch_bounds__(64,2) -> <=256 VGPR -> 2 waves/SIMD.
// Matvec: w_j broadcast via v_readlane (const lane idx after unroll), fmac with
// SGPR operand. Projection: Michelot/Newton fixed point == reference sort-proj.

#define NASSET 104
#define POWER_ITERS 20
#define N_ITERS 300

__device__ __forceinline__ float readl(float x, int lane) {
  return __uint_as_float(__builtin_amdgcn_readlane(__float_as_uint(x), lane));
}

__device__ __forceinline__ float wsum(float x) {
#pragma unroll
  for (int m = 32; m >= 1; m >>= 1) x += __shfl_xor(x, m, 64);
  return x;  // broadcast to all 64 lanes
}

__device__ __forceinline__ void matvec104(const float (&S0)[NASSET],
                                          const float (&S1)[NASSET],
                                          float x0, float x1,
                                          float &y0, float &y1) {
  // y[r] = sum_j S[r][j] * x[j]; x distributed as x0 = x[lane], x1 = x[64+lane]
  float a0 = 0.f, b0 = 0.f, a1 = 0.f, b1 = 0.f;
#pragma unroll
  for (int j = 0; j < NASSET; j += 2) {
    const float wja = readl((j < 64) ? x0 : x1, j & 63);
    const float wjb = readl(((j + 1) < 64) ? x0 : x1, (j + 1) & 63);
    a0 = fmaf(S0[j], wja, a0);
    a1 = fmaf(S1[j], wja, a1);
    b0 = fmaf(S0[j + 1], wjb, b0);
    b1 = fmaf(S1[j + 1], wjb, b1);
  }
  y0 = a0 + b0;
  y1 = a1 + b1;
}

__global__ __launch_bounds__(64, 2) void pgd_qp_kernel(
    const float *__restrict__ returns, const float *__restrict__ cov,
    float *__restrict__ out, int B) {
  const int b = blockIdx.x;
  if (b >= B) return;
  const int l = (int)threadIdx.x;
  const int r0 = l;
  const int r1 = 64 + l;
  const bool ok1 = (r1 < NASSET);
  const int r1c = ok1 ? r1 : (NASSET - 1);

  const float *Cb = cov + (size_t)b * NASSET * NASSET;
  const float mu0 = returns[(size_t)b * NASSET + r0];
  const float mu1 = returns[(size_t)b * NASSET + r1c];

  // ---- Load + symmetrize Sigma rows into registers ----
  // S[i][j] = 0.5*(C[i][j] + C[j][i]) + (i==j)*1e-6   (RISK_AVERSION==1)
  float S0[NASSET], S1[NASSET];
#pragma unroll
  for (int q = 0; q < NASSET / 4; ++q) {
    const float4 ra = *reinterpret_cast<const float4 *>(Cb + (size_t)r0 * NASSET + q * 4);
    const float4 rb = *reinterpret_cast<const float4 *>(Cb + (size_t)r1c * NASSET + q * 4);
#pragma unroll
    for (int u = 0; u < 4; ++u) {
      const int j = q * 4 + u;
      const float ca = Cb[(size_t)j * NASSET + r0];   // coalesced across lanes
      const float cb = Cb[(size_t)j * NASSET + r1c];
      const float rau = (u == 0) ? ra.x : (u == 1) ? ra.y : (u == 2) ? ra.z : ra.w;
      const float rbu = (u == 0) ? rb.x : (u == 1) ? rb.y : (u == 2) ? rb.z : rb.w;
      S0[j] = 0.5f * (rau + ca) + ((j == r0) ? 1e-6f : 0.f);
      S1[j] = 0.5f * (rbu + cb) + ((j == r1c) ? 1e-6f : 0.f);
    }
  }

  // ---- Power iteration for lambda_max ----
  const float inv_n = 1.0f / (float)NASSET;
  float v0 = inv_n, v1 = ok1 ? inv_n : 0.f;
#pragma unroll 1
  for (int pi = 0; pi < POWER_ITERS; ++pi) {
    float y0, y1;
    matvec104(S0, S1, v0, v1, y0, y1);
    y1 = ok1 ? y1 : 0.f;
    const float n2 = wsum(y0 * y0 + y1 * y1);
    const float inv = 1.0f / (sqrtf(n2) + 1e-12f);
    v0 = y0 * inv;
    v1 = ok1 ? (y1 * inv) : 0.f;
  }
  float z0, z1;
  matvec104(S0, S1, v0, v1, z0, z1);
  z1 = ok1 ? z1 : 0.f;
  const float lam = wsum(v0 * z0 + v1 * z1);
  const float eta = 1.0f / (2.2f * lam + 1e-8f);

  // ---- Projected gradient descent ----
  float w0 = inv_n, w1 = ok1 ? inv_n : 0.f;
#pragma unroll 1
  for (int it = 0; it < N_ITERS; ++it) {
    float y0, y1;
    matvec104(S0, S1, w0, w1, y0, y1);
    const float t0 = w0 - eta * (2.0f * y0 - mu0);
    const float t1 = ok1 ? (w1 - eta * (2.0f * y1 - mu1)) : -1e30f;

    // Simplex projection: Newton/Michelot fixed point on
    // theta = (sum_{t>theta} t - 1) / |{t>theta}|  (unique; == sort-based ref)
    const float s_all = wsum(t0 + (ok1 ? t1 : 0.f));
    float theta = (s_all - 1.0f) * inv_n;
    int kp = NASSET;
#pragma unroll 1
    for (int r = 0; r < 32; ++r) {
      const bool c0 = t0 > theta;
      const bool c1 = t1 > theta;  // t1 = -1e30 on invalid lanes -> false
      const float s2 = wsum((c0 ? t0 : 0.f) + (c1 ? t1 : 0.f));
      const int k = __popcll(__ballot(c0)) + __popcll(__ballot(c1));
      if (k == kp) break;  // active set unchanged -> theta is the fixed point
      theta = (s2 - 1.0f) / (float)k;
      kp = k;
    }
    w0 = fmaxf(t0 - theta, 0.f);
    w1 = ok1 ? fmaxf(t1 - theta, 0.f) : 0.f;
  }

  // ---- Store ----
  out[(size_t)b * NASSET + r0] = w0;
  if (ok1) out[(size_t)b * NASSET + r1] = w1;
}

extern "C" void kernel_launch(void *const *d_in, const int *in_sizes, int n_in,
                              void *d_out, int out_size, void *d_ws,
                              size_t ws_size, hipStream_t stream) {
  const float *returns = (const float *)d_in[0];
  const float *cov = (const float *)d_in[1];
  float *out = (float *)d_out;
  const int B = in_sizes[0] / NASSET;  // 4096
  pgd_qp_kernel<<<dim3(B), dim3(64), 0, stream>>>(returns, cov, out, B);
}

// Round 3
// 1145.304 us; speedup vs baseline: 1.5971x; 1.5971x over previous
//
#include <hip/hip_runtime.h>

// Portfolio PGD: B=4096 batches, n=104 assets, fp32.
// 1 wave (64 threads) per batch. Thread l owns Sigma rows l and 64+l in
// VGPR/AGPR (208 regs, unified file). launch_bounds(64,2) -> 2 waves/SIMD.
// R2: wave reduction via the classic GCN DPP idiom (row_shr + row_bcast,
// lane63 total, readlane broadcast). Pure VALU pipe, single-register —
// replaces R1's broken permlane_swap and R0's slow ds_bpermute butterfly.

#define NASSET 104
#define POWER_ITERS 20
#define N_ITERS 300

__device__ __forceinline__ float readl(float x, int lane) {
  return __uint_as_float(__builtin_amdgcn_readlane(__float_as_uint(x), lane));
}

template <int CTRL, int ROW_MASK>
__device__ __forceinline__ float dppf(float x) {
  // old=0: lanes masked off (row_mask) or out-of-bounds (bound_ctrl) yield 0,
  // which is the identity for the += below.
  return __int_as_float(__builtin_amdgcn_update_dpp(
      0, __float_as_int(x), CTRL, ROW_MASK, 0xf, true));
}

// Full-wave (64-lane) sum, broadcast to all lanes via SGPR. Pure VALU pipe.
__device__ __forceinline__ float wsum(float x) {
  x += dppf<0x111, 0xf>(x);  // row_shr:1
  x += dppf<0x112, 0xf>(x);  // row_shr:2
  x += dppf<0x114, 0xf>(x);  // row_shr:4
  x += dppf<0x118, 0xf>(x);  // row_shr:8  -> lane15 of each row = row sum
  x += dppf<0x142, 0xa>(x);  // row_bcast15 into rows 1,3
  x += dppf<0x143, 0xc>(x);  // row_bcast31 into rows 2,3 -> lane63 = total
  return readl(x, 63);
}

__device__ __forceinline__ void matvec104(const float (&S0)[NASSET],
                                          const float (&S1)[NASSET],
                                          float x0, float x1,
                                          float &y0, float &y1) {
  // y[r] = sum_j S[r][j] * x[j]; x distributed as x0 = x[lane], x1 = x[64+lane]
  float a0 = 0.f, b0 = 0.f, a1 = 0.f, b1 = 0.f;
#pragma unroll
  for (int j = 0; j < NASSET; j += 2) {
    const float wja = readl((j < 64) ? x0 : x1, j & 63);
    const float wjb = readl(((j + 1) < 64) ? x0 : x1, (j + 1) & 63);
    a0 = fmaf(S0[j], wja, a0);
    a1 = fmaf(S1[j], wja, a1);
    b0 = fmaf(S0[j + 1], wjb, b0);
    b1 = fmaf(S1[j + 1], wjb, b1);
  }
  y0 = a0 + b0;
  y1 = a1 + b1;
}

__global__ __launch_bounds__(64, 2) void pgd_qp_kernel(
    const float *__restrict__ returns, const float *__restrict__ cov,
    float *__restrict__ out, int B) {
  const int b = blockIdx.x;
  if (b >= B) return;
  const int l = (int)threadIdx.x;
  const int r0 = l;
  const int r1 = 64 + l;
  const bool ok1 = (r1 < NASSET);
  const int r1c = ok1 ? r1 : (NASSET - 1);

  const float *Cb = cov + (size_t)b * NASSET * NASSET;
  const float mu0 = returns[(size_t)b * NASSET + r0];
  const float mu1 = returns[(size_t)b * NASSET + r1c];

  // ---- Load + symmetrize Sigma rows into registers ----
  // S[i][j] = 0.5*(C[i][j] + C[j][i]) + (i==j)*1e-6   (RISK_AVERSION==1)
  float S0[NASSET], S1[NASSET];
#pragma unroll
  for (int q = 0; q < NASSET / 4; ++q) {
    const float4 ra = *reinterpret_cast<const float4 *>(Cb + (size_t)r0 * NASSET + q * 4);
    const float4 rb = *reinterpret_cast<const float4 *>(Cb + (size_t)r1c * NASSET + q * 4);
#pragma unroll
    for (int u = 0; u < 4; ++u) {
      const int j = q * 4 + u;
      const float ca = Cb[(size_t)j * NASSET + r0];   // coalesced across lanes
      const float cb = Cb[(size_t)j * NASSET + r1c];
      const float rau = (u == 0) ? ra.x : (u == 1) ? ra.y : (u == 2) ? ra.z : ra.w;
      const float rbu = (u == 0) ? rb.x : (u == 1) ? rb.y : (u == 2) ? rb.z : rb.w;
      S0[j] = 0.5f * (rau + ca) + ((j == r0) ? 1e-6f : 0.f);
      S1[j] = 0.5f * (rbu + cb) + ((j == r1c) ? 1e-6f : 0.f);
    }
  }

  // ---- Power iteration for lambda_max ----
  const float inv_n = 1.0f / (float)NASSET;
  float v0 = inv_n, v1 = ok1 ? inv_n : 0.f;
#pragma unroll 1
  for (int pi = 0; pi < POWER_ITERS; ++pi) {
    float y0, y1;
    matvec104(S0, S1, v0, v1, y0, y1);
    y1 = ok1 ? y1 : 0.f;
    const float n2 = wsum(y0 * y0 + y1 * y1);
    const float inv = 1.0f / (sqrtf(n2) + 1e-12f);
    v0 = y0 * inv;
    v1 = ok1 ? (y1 * inv) : 0.f;
  }
  float z0, z1;
  matvec104(S0, S1, v0, v1, z0, z1);
  z1 = ok1 ? z1 : 0.f;
  const float lam = wsum(v0 * z0 + v1 * z1);
  const float eta = 1.0f / (2.2f * lam + 1e-8f);

  // ---- Projected gradient descent ----
  float w0 = inv_n, w1 = ok1 ? inv_n : 0.f;
#pragma unroll 1
  for (int it = 0; it < N_ITERS; ++it) {
    float y0, y1;
    matvec104(S0, S1, w0, w1, y0, y1);
    const float t0 = w0 - eta * (2.0f * y0 - mu0);
    const float t1 = ok1 ? (w1 - eta * (2.0f * y1 - mu1)) : -1e30f;

    // Simplex projection: Michelot fixed point on
    // theta = (sum_{t>theta} t - 1) / |{t>theta}|  (fixed point == exact proj)
    const float s_all = wsum(t0 + (ok1 ? t1 : 0.f));
    float theta = (s_all - 1.0f) * inv_n;
    int kp = NASSET;
#pragma unroll 1
    for (int r = 0; r < 32; ++r) {
      const bool c0 = t0 > theta;
      const bool c1 = t1 > theta;  // t1 = -1e30 on invalid lanes -> false
      const float s2 = wsum((c0 ? t0 : 0.f) + (c1 ? t1 : 0.f));
      const int k = __popcll(__ballot(c0)) + __popcll(__ballot(c1));
      if (k == kp) break;  // active set unchanged -> theta is the fixed point
      theta = (s2 - 1.0f) * __builtin_amdgcn_rcpf((float)k);
      kp = k;
    }
    w0 = fmaxf(t0 - theta, 0.f);
    w1 = ok1 ? fmaxf(t1 - theta, 0.f) : 0.f;
  }

  // ---- Store ----
  out[(size_t)b * NASSET + r0] = w0;
  if (ok1) out[(size_t)b * NASSET + r1] = w1;
}

extern "C" void kernel_launch(void *const *d_in, const int *in_sizes, int n_in,
                              void *d_out, int out_size, void *d_ws,
                              size_t ws_size, hipStream_t stream) {
  const float *returns = (const float *)d_in[0];
  const float *cov = (const float *)d_in[1];
  float *out = (float *)d_out;
  const int B = in_sizes[0] / NASSET;  // 4096
  pgd_qp_kernel<<<dim3(B), dim3(64), 0, stream>>>(returns, cov, out, B);
}

// Round 4
// 1023.442 us; speedup vs baseline: 1.7872x; 1.1191x over previous
//
#include <hip/hip_runtime.h>

// Portfolio PGD: B=4096 batches, n=104 assets, fp32.
// 1 wave (64 threads) per batch. Thread l owns Sigma rows l and 64+l,
// stored column-pair-packed as float2 for v_pk_fma_f32 (2 FMA / issue slot).
// Wave reductions: GCN DPP idiom (row_shr + row_bcast + readlane), VALU pipe.

#define NASSET 104
#define POWER_ITERS 20
#define N_ITERS 300
#define NPAIR (NASSET / 2)

typedef float v2f __attribute__((ext_vector_type(2)));

__device__ __forceinline__ float readl(float x, int lane) {
  return __uint_as_float(__builtin_amdgcn_readlane(__float_as_uint(x), lane));
}

template <int CTRL, int ROW_MASK>
__device__ __forceinline__ float dppf(float x) {
  return __int_as_float(__builtin_amdgcn_update_dpp(
      0, __float_as_int(x), CTRL, ROW_MASK, 0xf, true));
}

// Full-wave (64-lane) sum, broadcast to all lanes via SGPR. Pure VALU pipe.
__device__ __forceinline__ float wsum(float x) {
  x += dppf<0x111, 0xf>(x);  // row_shr:1
  x += dppf<0x112, 0xf>(x);  // row_shr:2
  x += dppf<0x114, 0xf>(x);  // row_shr:4
  x += dppf<0x118, 0xf>(x);  // row_shr:8  -> lane15 of each row = row sum
  x += dppf<0x142, 0xa>(x);  // row_bcast15 into rows 1,3
  x += dppf<0x143, 0xc>(x);  // row_bcast31 into rows 2,3 -> lane63 = total
  return readl(x, 63);
}

__device__ __forceinline__ void matvec104(const v2f (&SA)[NPAIR],
                                          const v2f (&SB)[NPAIR],
                                          float x0, float x1,
                                          float &y0, float &y1) {
  // y[r] = sum_j S[r][j] * x[j]; x distributed as x0 = x[lane], x1 = x[64+lane]
  v2f acc0 = {0.f, 0.f}, acc1 = {0.f, 0.f};
#pragma unroll
  for (int q = 0; q < NPAIR; ++q) {
    const int j = 2 * q;  // pairs never straddle the 63/64 lane boundary
    const float wja = readl((j < 64) ? x0 : x1, j & 63);
    const float wjb = readl(((j + 1) < 64) ? x0 : x1, (j + 1) & 63);
    const v2f wv = {wja, wjb};
    acc0 = __builtin_elementwise_fma(SA[q], wv, acc0);  // v_pk_fma_f32
    acc1 = __builtin_elementwise_fma(SB[q], wv, acc1);
  }
  y0 = acc0.x + acc0.y;  // even-chain + odd-chain: same order as R2
  y1 = acc1.x + acc1.y;
}

__global__ __launch_bounds__(64, 2) void pgd_qp_kernel(
    const float *__restrict__ returns, const float *__restrict__ cov,
    float *__restrict__ out, int B) {
  const int b = blockIdx.x;
  if (b >= B) return;
  const int l = (int)threadIdx.x;
  const int r0 = l;
  const int r1 = 64 + l;
  const bool ok1 = (r1 < NASSET);
  const int r1c = ok1 ? r1 : (NASSET - 1);

  const float *Cb = cov + (size_t)b * NASSET * NASSET;
  const float mu0 = returns[(size_t)b * NASSET + r0];
  const float mu1 = returns[(size_t)b * NASSET + r1c];

  // ---- Load + symmetrize Sigma rows into registers (column-pair packed) ----
  // S[i][j] = 0.5*(C[i][j] + C[j][i]) + (i==j)*1e-6   (RISK_AVERSION==1)
  v2f SA[NPAIR], SB[NPAIR];
#pragma unroll
  for (int q = 0; q < NASSET / 4; ++q) {
    const float4 ra = *reinterpret_cast<const float4 *>(Cb + (size_t)r0 * NASSET + q * 4);
    const float4 rb = *reinterpret_cast<const float4 *>(Cb + (size_t)r1c * NASSET + q * 4);
    float sa[4], sb[4];
#pragma unroll
    for (int u = 0; u < 4; ++u) {
      const int j = q * 4 + u;
      const float ca = Cb[(size_t)j * NASSET + r0];   // coalesced across lanes
      const float cb = Cb[(size_t)j * NASSET + r1c];
      const float rau = (u == 0) ? ra.x : (u == 1) ? ra.y : (u == 2) ? ra.z : ra.w;
      const float rbu = (u == 0) ? rb.x : (u == 1) ? rb.y : (u == 2) ? rb.z : rb.w;
      sa[u] = 0.5f * (rau + ca) + ((j == r0) ? 1e-6f : 0.f);
      sb[u] = 0.5f * (rbu + cb) + ((j == r1c) ? 1e-6f : 0.f);
    }
    SA[2 * q] = (v2f){sa[0], sa[1]};
    SA[2 * q + 1] = (v2f){sa[2], sa[3]};
    SB[2 * q] = (v2f){sb[0], sb[1]};
    SB[2 * q + 1] = (v2f){sb[2], sb[3]};
  }

  // ---- Power iteration for lambda_max ----
  const float inv_n = 1.0f / (float)NASSET;
  float v0 = inv_n, v1 = ok1 ? inv_n : 0.f;
#pragma unroll 1
  for (int pi = 0; pi < POWER_ITERS; ++pi) {
    float y0, y1;
    matvec104(SA, SB, v0, v1, y0, y1);
    y1 = ok1 ? y1 : 0.f;
    const float n2 = wsum(y0 * y0 + y1 * y1);
    const float inv = 1.0f / (sqrtf(n2) + 1e-12f);
    v0 = y0 * inv;
    v1 = ok1 ? (y1 * inv) : 0.f;
  }
  float z0, z1;
  matvec104(SA, SB, v0, v1, z0, z1);
  z1 = ok1 ? z1 : 0.f;
  const float lam = wsum(v0 * z0 + v1 * z1);
  const float eta = 1.0f / (2.2f * lam + 1e-8f);

  // Folded gradient constants: t = w - eta*(2*Sw - mu) = fma(-2eta, Sw, w + eta*mu)
  const float ne2 = -2.0f * eta;
  const float em0 = eta * mu0;
  const float em1 = eta * mu1;

  // ---- Projected gradient descent ----
  float w0 = inv_n, w1 = ok1 ? inv_n : 0.f;
#pragma unroll 1
  for (int it = 0; it < N_ITERS; ++it) {
    float y0, y1;
    matvec104(SA, SB, w0, w1, y0, y1);
    const float t0 = fmaf(ne2, y0, w0 + em0);
    const float t1 = ok1 ? fmaf(ne2, y1, w1 + em1) : -1e30f;

    // Simplex projection: Michelot fixed point on
    // theta = (sum_{t>theta} t - 1) / |{t>theta}|  (fixed point == exact proj)
    const float s_all = wsum(t0 + (ok1 ? t1 : 0.f));
    float theta = (s_all - 1.0f) * inv_n;
    int kp = NASSET;
#pragma unroll 1
    for (int r = 0; r < 32; ++r) {
      const bool c0 = t0 > theta;
      const bool c1 = t1 > theta;  // t1 = -1e30 on invalid lanes -> false
      const float s2 = wsum((c0 ? t0 : 0.f) + (c1 ? t1 : 0.f));
      const int k = __popcll(__ballot(c0)) + __popcll(__ballot(c1));
      if (k == kp) break;  // active set unchanged -> theta is the fixed point
      theta = (s2 - 1.0f) * __builtin_amdgcn_rcpf((float)k);
      kp = k;
    }
    w0 = fmaxf(t0 - theta, 0.f);
    w1 = ok1 ? fmaxf(t1 - theta, 0.f) : 0.f;
  }

  // ---- Store ----
  out[(size_t)b * NASSET + r0] = w0;
  if (ok1) out[(size_t)b * NASSET + r1] = w1;
}

extern "C" void kernel_launch(void *const *d_in, const int *in_sizes, int n_in,
                              void *d_out, int out_size, void *d_ws,
                              size_t ws_size, hipStream_t stream) {
  const float *returns = (const float *)d_in[0];
  const float *cov = (const float *)d_in[1];
  float *out = (float *)d_out;
  const int B = in_sizes[0] / NASSET;  // 4096
  pgd_qp_kernel<<<dim3(B), dim3(64), 0, stream>>>(returns, cov, out, B);
}

// Round 5
// 875.540 us; speedup vs baseline: 2.0892x; 1.1689x over previous
//
#include <hip/hip_runtime.h>

// Portfolio PGD: B=4096 batches, n=104 assets, fp32.
// 1 wave (64 threads) per batch. Thread l owns Sigma rows l and 64+l,
// column-pair packed as float2 for v_pk_fma_f32 (2 FMA / issue slot).
// R4: x-vector broadcast via wave-private LDS (uniform-address ds_read_b128)
// instead of 104 v_readlane per matvec (SGPR hazard stalls, VALU slots).
// Wave reductions: GCN DPP idiom (row_shr + row_bcast + readlane).

#define NASSET 104
#define POWER_ITERS 20
#define N_ITERS 300
#define NPAIR (NASSET / 2)

typedef float v2f __attribute__((ext_vector_type(2)));

__device__ __forceinline__ float readl(float x, int lane) {
  return __uint_as_float(__builtin_amdgcn_readlane(__float_as_uint(x), lane));
}

template <int CTRL, int ROW_MASK>
__device__ __forceinline__ float dppf(float x) {
  return __int_as_float(__builtin_amdgcn_update_dpp(
      0, __float_as_int(x), CTRL, ROW_MASK, 0xf, true));
}

// Full-wave (64-lane) sum, broadcast to all lanes via SGPR. Pure VALU pipe.
__device__ __forceinline__ float wsum(float x) {
  x += dppf<0x111, 0xf>(x);  // row_shr:1
  x += dppf<0x112, 0xf>(x);  // row_shr:2
  x += dppf<0x114, 0xf>(x);  // row_shr:4
  x += dppf<0x118, 0xf>(x);  // row_shr:8  -> lane15 of each row = row sum
  x += dppf<0x142, 0xa>(x);  // row_bcast15 into rows 1,3
  x += dppf<0x143, 0xc>(x);  // row_bcast31 into rows 2,3 -> lane63 = total
  return readl(x, 63);
}

// y[r] = sum_j S[r][j] * x[j], x read from wave-private LDS (broadcast reads).
__device__ __forceinline__ void matvec104(const v2f (&SA)[NPAIR],
                                          const v2f (&SB)[NPAIR],
                                          const float *__restrict__ xs,
                                          float &y0, float &y1) {
  v2f acc0 = {0.f, 0.f}, acc1 = {0.f, 0.f};
#pragma unroll
  for (int q = 0; q < NPAIR; q += 2) {
    const float4 xq = *reinterpret_cast<const float4 *>(xs + 2 * q);
    const v2f wa = {xq.x, xq.y};
    const v2f wb = {xq.z, xq.w};
    acc0 = __builtin_elementwise_fma(SA[q], wa, acc0);
    acc1 = __builtin_elementwise_fma(SB[q], wa, acc1);
    acc0 = __builtin_elementwise_fma(SA[q + 1], wb, acc0);
    acc1 = __builtin_elementwise_fma(SB[q + 1], wb, acc1);
  }
  y0 = acc0.x + acc0.y;  // even-chain + odd-chain: same order as R3
  y1 = acc1.x + acc1.y;
}

__global__ __launch_bounds__(64, 2) void pgd_qp_kernel(
    const float *__restrict__ returns, const float *__restrict__ cov,
    float *__restrict__ out, int B) {
  const int b = blockIdx.x;
  if (b >= B) return;
  const int l = (int)threadIdx.x;
  const int r0 = l;
  const int r1 = 64 + l;
  const bool ok1 = (r1 < NASSET);
  const int r1c = ok1 ? r1 : (NASSET - 1);

  __shared__ __align__(16) float xs[128];  // wave-private x broadcast buffer

  const float *Cb = cov + (size_t)b * NASSET * NASSET;
  const float mu0 = returns[(size_t)b * NASSET + r0];
  const float mu1 = returns[(size_t)b * NASSET + r1c];

  // ---- Load + symmetrize Sigma rows into registers (column-pair packed) ----
  // S[i][j] = 0.5*(C[i][j] + C[j][i]) + (i==j)*1e-6   (RISK_AVERSION==1)
  v2f SA[NPAIR], SB[NPAIR];
#pragma unroll
  for (int q = 0; q < NASSET / 4; ++q) {
    const float4 ra = *reinterpret_cast<const float4 *>(Cb + (size_t)r0 * NASSET + q * 4);
    const float4 rb = *reinterpret_cast<const float4 *>(Cb + (size_t)r1c * NASSET + q * 4);
    float sa[4], sb[4];
#pragma unroll
    for (int u = 0; u < 4; ++u) {
      const int j = q * 4 + u;
      const float ca = Cb[(size_t)j * NASSET + r0];   // coalesced across lanes
      const float cb = Cb[(size_t)j * NASSET + r1c];
      const float rau = (u == 0) ? ra.x : (u == 1) ? ra.y : (u == 2) ? ra.z : ra.w;
      const float rbu = (u == 0) ? rb.x : (u == 1) ? rb.y : (u == 2) ? rb.z : rb.w;
      sa[u] = 0.5f * (rau + ca) + ((j == r0) ? 1e-6f : 0.f);
      sb[u] = 0.5f * (rbu + cb) + ((j == r1c) ? 1e-6f : 0.f);
    }
    SA[2 * q] = (v2f){sa[0], sa[1]};
    SA[2 * q + 1] = (v2f){sa[2], sa[3]};
    SB[2 * q] = (v2f){sb[0], sb[1]};
    SB[2 * q + 1] = (v2f){sb[2], sb[3]};
  }

  // ---- Power iteration for lambda_max ----
  const float inv_n = 1.0f / (float)NASSET;
  float v0 = inv_n, v1 = ok1 ? inv_n : 0.f;
#pragma unroll 1
  for (int pi = 0; pi < POWER_ITERS; ++pi) {
    xs[l] = v0;
    xs[64 + l] = v1;  // lanes >=40 write zeros into the unused tail
    __syncthreads();  // 1-wave block: compiles to an lgkmcnt drain
    float y0, y1;
    matvec104(SA, SB, xs, y0, y1);
    y1 = ok1 ? y1 : 0.f;
    const float n2 = wsum(y0 * y0 + y1 * y1);
    const float inv = 1.0f / (sqrtf(n2) + 1e-12f);
    v0 = y0 * inv;
    v1 = ok1 ? (y1 * inv) : 0.f;
  }
  {
    xs[l] = v0;
    xs[64 + l] = v1;
    __syncthreads();
  }
  float z0, z1;
  matvec104(SA, SB, xs, z0, z1);
  z1 = ok1 ? z1 : 0.f;
  const float lam = wsum(v0 * z0 + v1 * z1);
  const float eta = 1.0f / (2.2f * lam + 1e-8f);

  // Folded gradient constants: t = w - eta*(2*Sw - mu) = fma(-2eta, Sw, w + eta*mu)
  const float ne2 = -2.0f * eta;
  const float em0 = eta * mu0;
  const float em1 = eta * mu1;

  // ---- Projected gradient descent ----
  float w0 = inv_n, w1 = ok1 ? inv_n : 0.f;
#pragma unroll 1
  for (int it = 0; it < N_ITERS; ++it) {
    xs[l] = w0;
    xs[64 + l] = w1;
    __syncthreads();
    float y0, y1;
    matvec104(SA, SB, xs, y0, y1);
    const float t0 = fmaf(ne2, y0, w0 + em0);
    const float t1 = ok1 ? fmaf(ne2, y1, w1 + em1) : -1e30f;

    // Simplex projection: Michelot fixed point on
    // theta = (sum_{t>theta} t - 1) / |{t>theta}|  (fixed point == exact proj)
    const float s_all = wsum(t0 + (ok1 ? t1 : 0.f));
    float theta = (s_all - 1.0f) * inv_n;
    int kp = NASSET;
#pragma unroll 1
    for (int r = 0; r < 32; ++r) {
      const bool c0 = t0 > theta;
      const bool c1 = t1 > theta;  // t1 = -1e30 on invalid lanes -> false
      const float s2 = wsum((c0 ? t0 : 0.f) + (c1 ? t1 : 0.f));
      const int k = __popcll(__ballot(c0)) + __popcll(__ballot(c1));
      if (k == kp) break;  // active set unchanged -> theta is the fixed point
      theta = (s2 - 1.0f) * __builtin_amdgcn_rcpf((float)k);
      kp = k;
    }
    w0 = fmaxf(t0 - theta, 0.f);
    w1 = ok1 ? fmaxf(t1 - theta, 0.f) : 0.f;
  }

  // ---- Store ----
  out[(size_t)b * NASSET + r0] = w0;
  if (ok1) out[(size_t)b * NASSET + r1] = w1;
}

extern "C" void kernel_launch(void *const *d_in, const int *in_sizes, int n_in,
                              void *d_out, int out_size, void *d_ws,
                              size_t ws_size, hipStream_t stream) {
  const float *returns = (const float *)d_in[0];
  const float *cov = (const float *)d_in[1];
  float *out = (float *)d_out;
  const int B = in_sizes[0] / NASSET;  // 4096
  pgd_qp_kernel<<<dim3(B), dim3(64), 0, stream>>>(returns, cov, out, B);
}

// Round 6
// 492.382 us; speedup vs baseline: 3.7149x; 1.7782x over previous
//
#include <hip/hip_runtime.h>

// Portfolio PGD: B=4096 batches, n=104 assets.
// 1 wave per batch. Thread l owns Sigma rows l and 64+l in PACKED FP16
// (104 VGPRs vs 208 fp32) -> whole kernel fits 128 VGPR -> 4 waves/SIMD,
// no AGPR round-trips, no scratch spill. Matvec: v_dot2_f32_f16 (2 fp16
// MAC, fp32 accum) fed by uniform-address LDS broadcast of x (fp16, 13
// ds_read_b128). Reductions: GCN DPP row_shr/row_bcast idiom.
// Michelot projection warm-started from previous iteration's theta
// (fixed-point map converges from any start -> exact).

#define NASSET 104
#define POWER_ITERS 20
#define N_ITERS 300

typedef _Float16 v2h __attribute__((ext_vector_type(2)));

__device__ __forceinline__ float readl(float x, int lane) {
  return __uint_as_float(__builtin_amdgcn_readlane(__float_as_uint(x), lane));
}

template <int CTRL, int ROW_MASK>
__device__ __forceinline__ float dppf(float x) {
  return __int_as_float(__builtin_amdgcn_update_dpp(
      0, __float_as_int(x), CTRL, ROW_MASK, 0xf, true));
}

// Full-wave (64-lane) sum, broadcast to all lanes via SGPR. Pure VALU pipe.
__device__ __forceinline__ float wsum(float x) {
  x += dppf<0x111, 0xf>(x);  // row_shr:1
  x += dppf<0x112, 0xf>(x);  // row_shr:2
  x += dppf<0x114, 0xf>(x);  // row_shr:4
  x += dppf<0x118, 0xf>(x);  // row_shr:8  -> lane15 of each row = row sum
  x += dppf<0x142, 0xa>(x);  // row_bcast15 into rows 1,3
  x += dppf<0x143, 0xc>(x);  // row_bcast31 into rows 2,3 -> lane63 = total
  return readl(x, 63);
}

// y[r] = sum_j S[r][j]*x[j]; Sigma fp16-packed, x broadcast from LDS (fp16).
__device__ __forceinline__ void matvec104(const v2h (&SA)[52],
                                          const v2h (&SB)[52],
                                          const _Float16 *__restrict__ xs,
                                          float &y0, float &y1) {
  float a0 = 0.f, b0 = 0.f, a1 = 0.f, b1 = 0.f;  // 2 chains/row (latency)
#pragma unroll
  for (int i = 0; i < 13; ++i) {
    const uint4 q = *reinterpret_cast<const uint4 *>(xs + 8 * i);
    const v2h x0 = __builtin_bit_cast(v2h, q.x);
    const v2h x1 = __builtin_bit_cast(v2h, q.y);
    const v2h x2 = __builtin_bit_cast(v2h, q.z);
    const v2h x3 = __builtin_bit_cast(v2h, q.w);
    a0 = __builtin_amdgcn_fdot2(SA[4 * i + 0], x0, a0, false);
    a1 = __builtin_amdgcn_fdot2(SB[4 * i + 0], x0, a1, false);
    b0 = __builtin_amdgcn_fdot2(SA[4 * i + 1], x1, b0, false);
    b1 = __builtin_amdgcn_fdot2(SB[4 * i + 1], x1, b1, false);
    a0 = __builtin_amdgcn_fdot2(SA[4 * i + 2], x2, a0, false);
    a1 = __builtin_amdgcn_fdot2(SB[4 * i + 2], x2, a1, false);
    b0 = __builtin_amdgcn_fdot2(SA[4 * i + 3], x3, b0, false);
    b1 = __builtin_amdgcn_fdot2(SB[4 * i + 3], x3, b1, false);
  }
  y0 = a0 + b0;
  y1 = a1 + b1;
}

__global__ __launch_bounds__(64, 4) void pgd_qp_kernel(
    const float *__restrict__ returns, const float *__restrict__ cov,
    float *__restrict__ out, int B) {
  const int b = blockIdx.x;
  if (b >= B) return;
  const int l = (int)threadIdx.x;
  const int r0 = l;
  const int r1 = 64 + l;
  const bool ok1 = (r1 < NASSET);
  const int r1c = ok1 ? r1 : (NASSET - 1);

  __shared__ __align__(16) _Float16 xs[128];  // x broadcast buffer (fp16)

  const float *Cb = cov + (size_t)b * NASSET * NASSET;
  const float mu0 = returns[(size_t)b * NASSET + r0];
  const float mu1 = returns[(size_t)b * NASSET + r1c];

  // ---- Load + symmetrize Sigma rows -> packed fp16 registers ----
  // S[i][j] = 0.5*(C[i][j] + C[j][i]) + (i==j)*1e-6   (RISK_AVERSION==1)
  v2h SA[52], SB[52];
#pragma unroll
  for (int q = 0; q < NASSET / 4; ++q) {
    const float4 ra = *reinterpret_cast<const float4 *>(Cb + (size_t)r0 * NASSET + q * 4);
    const float4 rb = *reinterpret_cast<const float4 *>(Cb + (size_t)r1c * NASSET + q * 4);
    float sa[4], sb[4];
#pragma unroll
    for (int u = 0; u < 4; ++u) {
      const int j = q * 4 + u;
      const float ca = Cb[(size_t)j * NASSET + r0];   // coalesced across lanes
      const float cb = Cb[(size_t)j * NASSET + r1c];
      const float rau = (u == 0) ? ra.x : (u == 1) ? ra.y : (u == 2) ? ra.z : ra.w;
      const float rbu = (u == 0) ? rb.x : (u == 1) ? rb.y : (u == 2) ? rb.z : rb.w;
      sa[u] = 0.5f * (rau + ca) + ((j == r0) ? 1e-6f : 0.f);
      sb[u] = 0.5f * (rbu + cb) + ((j == r1c) ? 1e-6f : 0.f);
    }
    SA[2 * q] = (v2h){(_Float16)sa[0], (_Float16)sa[1]};
    SA[2 * q + 1] = (v2h){(_Float16)sa[2], (_Float16)sa[3]};
    SB[2 * q] = (v2h){(_Float16)sb[0], (_Float16)sb[1]};
    SB[2 * q + 1] = (v2h){(_Float16)sb[2], (_Float16)sb[3]};
  }

  // ---- Power iteration for lambda_max ----
  const float inv_n = 1.0f / (float)NASSET;
  float v0 = inv_n, v1 = ok1 ? inv_n : 0.f;
#pragma unroll 1
  for (int pi = 0; pi < POWER_ITERS; ++pi) {
    xs[l] = (_Float16)v0;
    xs[64 + l] = (_Float16)v1;  // cols 104..127 stay 0 (v1==0 when !ok1)
    __syncthreads();
    float y0, y1;
    matvec104(SA, SB, xs, y0, y1);
    y1 = ok1 ? y1 : 0.f;
    const float n2 = wsum(y0 * y0 + y1 * y1);
    const float inv = 1.0f / (sqrtf(n2) + 1e-12f);
    v0 = y0 * inv;
    v1 = ok1 ? (y1 * inv) : 0.f;
  }
  {
    xs[l] = (_Float16)v0;
    xs[64 + l] = (_Float16)v1;
    __syncthreads();
  }
  float z0, z1;
  matvec104(SA, SB, xs, z0, z1);
  z1 = ok1 ? z1 : 0.f;
  const float lam = wsum(v0 * z0 + v1 * z1);
  const float eta = 1.0f / (2.2f * lam + 1e-8f);

  // Folded gradient constants: t = fma(-2eta, Sw, w + eta*mu)
  const float ne2 = -2.0f * eta;
  const float em0 = eta * mu0;
  const float em1 = eta * mu1;

  // ---- Projected gradient descent ----
  float w0 = inv_n, w1 = ok1 ? inv_n : 0.f;
  float theta_ws = 0.f;  // warm-start threshold carried across iterations
#pragma unroll 1
  for (int it = 0; it < N_ITERS; ++it) {
    xs[l] = (_Float16)w0;
    xs[64 + l] = (_Float16)w1;
    __syncthreads();
    float y0, y1;
    matvec104(SA, SB, xs, y0, y1);
    const float t0 = fmaf(ne2, y0, w0 + em0);
    const float t1 = ok1 ? fmaf(ne2, y1, w1 + em1) : -1e30f;

    // Michelot fixed point: theta = (sum_{t>theta} t - 1)/k. The map
    // converges monotonically to the unique theta* from ANY start, so
    // warm-starting from the previous iteration's theta is exact.
    float theta = (it == 0)
                      ? (wsum(t0 + (ok1 ? t1 : 0.f)) - 1.0f) * inv_n
                      : theta_ws;
    int kp = -1;
#pragma unroll 1
    for (int r = 0; r < 32; ++r) {
      const bool c0 = t0 > theta;
      const bool c1 = t1 > theta;  // t1 = -1e30 on invalid lanes -> false
      const float s2 = wsum((c0 ? t0 : 0.f) + (c1 ? t1 : 0.f));
      const int k = __popcll(__ballot(c0)) + __popcll(__ballot(c1));
      if (k == kp) break;  // active set stable -> theta is the fixed point
      if (k == 0) {        // warm start above max(t): cold restart (rare)
        theta = (wsum(t0 + (ok1 ? t1 : 0.f)) - 1.0f) * inv_n;
        kp = -1;
        continue;
      }
      theta = (s2 - 1.0f) * __builtin_amdgcn_rcpf((float)k);
      kp = k;
    }
    theta_ws = theta;
    w0 = fmaxf(t0 - theta, 0.f);
    w1 = ok1 ? fmaxf(t1 - theta, 0.f) : 0.f;
  }

  // ---- Store ----
  out[(size_t)b * NASSET + r0] = w0;
  if (ok1) out[(size_t)b * NASSET + r1] = w1;
}

extern "C" void kernel_launch(void *const *d_in, const int *in_sizes, int n_in,
                              void *d_out, int out_size, void *d_ws,
                              size_t ws_size, hipStream_t stream) {
  const float *returns = (const float *)d_in[0];
  const float *cov = (const float *)d_in[1];
  float *out = (float *)d_out;
  const int B = in_sizes[0] / NASSET;  // 4096
  pgd_qp_kernel<<<dim3(B), dim3(64), 0, stream>>>(returns, cov, out, B);
}